// Round 1
// baseline (122632.178 us; speedup 1.0000x reference)
//
#include <hip/hip_runtime.h>
#include <stdint.h>
#include <stddef.h>

// ---------------- problem constants ----------------
#define B_   64
#define L_   512
#define E_   512
#define HL_  1024
#define HS_  256
#define NC_  5
#define KL_  (E_ + HL_)   // 1536
#define KS_  (E_ + HS_)   // 768

// ---------------- workspace layout (bytes) — ~102.7 MB total ----------------
#define OFF_AHI   0ull            // [L][B][E] u16      33,554,432
#define OFF_ALO   33554432ull     //                    33,554,432
#define OFF_WLHI  67108864ull     // [4096][1536] u16   12,582,912
#define OFF_WLLO  79691776ull     //                    12,582,912
#define OFF_WSHI  92274688ull     // [1024][768]  u16    1,572,864
#define OFF_WSLO  93847552ull     //                     1,572,864
#define OFF_PARTL 95420416ull     // [64 dt][8 s][64 rr][64 b] f32  8,388,608
#define OFF_PARTS 103809024ull    // [16 dt][4 s][64 rr][64 b] f32  1,048,576
// ---- state block (zeroed every launch) ----
#define OFF_CL    104857600ull    // [1024 d][64 b] f32   262,144
#define OFF_HF    105119744ull    // [1024 d][64 b] f32   262,144  (prev/new large h, f32)
#define OFF_CS    105381888ull    // [256 d][64 b]  f32    65,536
#define OFF_PACC  105447424ull    // [512 t][64 b][2] f32 262,144
#define OFF_HHI   105709568ull    // [2 buf][64 b][1024 d] u16 262,144
#define OFF_HLO   105971712ull    //                      262,144
#define OFF_HSHI  106233856ull    // [2 buf][64 b][256 d] u16  65,536
#define OFF_HSLO  106299392ull    //                       65,536
#define OFF_CNT   106364928ull    // [512 t][64 dt] int   131,072  (gemm arrivals)
#define OFF_CNT2  106496000ull    // [512 t][64 dt] int   131,072  (pointwise finishers)
#define OFF_DONE  106627072ull    // [512 t][64 dt] int   131,072  (dtile step complete)
#define OFF_PPART 106758144ull    // [64 dt][8 s][64 b][2] f32 262,144
#define OFF_STATE_END 107020288ull
// ---- non-zeroed scratch ----
#define OFF_PE    107020288ull    // [512 t][64 b][2] f32 262,144
#define OFF_RSEQ  107282432ull    // [512 t][64 b][2] f32 262,144
#define OFF_Z1    107544576ull    // [64][512] f32        131,072
// end = 107,675,648

typedef __attribute__((ext_vector_type(8))) short bf16x8;   // 8 bf16 in 4 VGPRs
typedef __attribute__((ext_vector_type(4))) float f32x4;

__device__ __forceinline__ uint16_t f2bf(float f) {
  union { float f; uint32_t u; } v; v.f = f;
  uint32_t r = v.u + 0x7FFFu + ((v.u >> 16) & 1u);
  return (uint16_t)(r >> 16);
}
__device__ __forceinline__ float bf2f(uint16_t h) {
  union { uint32_t u; float f; } v; v.u = ((uint32_t)h) << 16; return v.f;
}
__device__ __forceinline__ float sigm(float x) { return 1.0f / (1.0f + expf(-x)); }

// ---------------- setup kernels (unchanged logic) ----------------

__global__ __launch_bounds__(256) void k_convw(
    const float* __restrict__ Wihl, const float* __restrict__ Whhl,
    const float* __restrict__ Wihs, const float* __restrict__ Whhs,
    uint16_t* __restrict__ Wl_hi, uint16_t* __restrict__ Wl_lo,
    uint16_t* __restrict__ Ws_hi, uint16_t* __restrict__ Ws_lo) {
  const int N1 = 4096 * KL_;
  const int N2 = 1024 * KS_;
  int idx = blockIdx.x * 256 + threadIdx.x;
  if (idx < N1) {
    int row = idx / KL_, k = idx - row * KL_;
    float v = (k < E_) ? Wihl[row * E_ + k] : Whhl[row * HL_ + (k - E_)];
    uint16_t hi = f2bf(v);
    Wl_hi[idx] = hi;
    Wl_lo[idx] = f2bf(v - bf2f(hi));
  } else if (idx < N1 + N2) {
    int j = idx - N1;
    int row = j / KS_, k = j - row * KS_;
    float v = (k < E_) ? Wihs[row * E_ + k] : Whhs[row * HS_ + (k - E_)];
    uint16_t hi = f2bf(v);
    Ws_hi[j] = hi;
    Ws_lo[j] = f2bf(v - bf2f(hi));
  }
}

__global__ __launch_bounds__(256) void k_embed(
    const int* __restrict__ x, const float* __restrict__ emb,
    uint16_t* __restrict__ Ahi, uint16_t* __restrict__ Alo) {
  int idx = blockIdx.x * 256 + threadIdx.x;
  int t = idx >> 15;
  int rem = idx & 32767;
  int b = rem >> 9;
  int k = rem & 511;
  int tok = x[b * L_ + t];
  float v = emb[(size_t)tok * E_ + k];
  uint16_t hi = f2bf(v);
  Ahi[idx] = hi;
  Alo[idx] = f2bf(v - bf2f(hi));
}

__global__ __launch_bounds__(256) void k_zero(uint32_t* __restrict__ p, int nwords) {
  int idx = blockIdx.x * 256 + threadIdx.x;
  if (idx < nwords) p[idx] = 0u;
}

__global__ __launch_bounds__(256) void k_rseq(
    const float* __restrict__ gum, float* __restrict__ rseq) {
  int idx = blockIdx.x * 256 + threadIdx.x;       // t*64+b
  int t = idx >> 6, b = idx & 63;
  float u0 = gum[(b * L_ + t) * 2 + 0];
  float u1 = gum[(b * L_ + t) * 2 + 1];
  float g0 = -logf(-logf(u0));
  float g1 = -logf(-logf(u1));
  float m = fmaxf(g0, g1);
  float e0 = expf(g0 - m), e1 = expf(g1 - m);
  float inv = 1.0f / (e0 + e1);
  rseq[idx * 2 + 0] = e0 * inv;
  rseq[idx * 2 + 1] = e1 * inv;
}

__global__ __launch_bounds__(256) void k_pe(
    const int* __restrict__ x, const float* __restrict__ emb,
    const float* __restrict__ Wp, float* __restrict__ Pe) {
  int idx = blockIdx.x * 256 + threadIdx.x;       // t*64+b
  int t = idx >> 6, b = idx & 63;
  int tok = x[b * L_ + t];
  const float* row = emb + (size_t)tok * E_;
  float a0 = 0.f, a1 = 0.f;
  for (int k = 0; k < E_; ++k) {
    float e = row[k];
    a0 += e * Wp[k];
    a1 += e * Wp[(E_ + 2 * HL_) + k];
  }
  Pe[idx * 2 + 0] = a0;
  Pe[idx * 2 + 1] = a1;
}

// ---------------- persistent scan kernel ----------------
// Grid 576 blocks x 64 threads, all resident (48KB LDS -> 3 blocks/CU -> 768 slots).
//   bid <  512 : large cell, D = bid>>3 (d-tile of 16 d's), s = bid&7 (K-slice of 192)
//   bid >= 512 : small cell, D = (bid-512)>>2 (D<16),       s = (bid-512)&3
// Block rows = gates {i,f,g,o} x 16 d's of its d-tile (row remap is a free gather).
// Weights (hi+lo) for the block's 64 rows x 192 k live in LDS in fragment order.
// Per step: GEMM -> partial -> arrive cnt[t][D]; large blocks spin cnt full,
// do pointwise for d_lo {2s,2s+1}; last finisher (cnt2) publishes done[t][D];
// everyone spins on the 64 done flags of step t-1 before step t's GEMM.
// h (bf16 hi/lo) is double-buffered: GEMM(t) reads buf t&1, pointwise(t) writes (t+1)&1.
__global__ __launch_bounds__(64, 2) void k_scan(
    char* __restrict__ ws,
    const float* __restrict__ bihl, const float* __restrict__ bhhl,
    const float* __restrict__ bihs, const float* __restrict__ bhhs,
    const float* __restrict__ Wp, float* __restrict__ out_h) {
  const uint16_t* Ahi = (const uint16_t*)(ws + OFF_AHI);
  const uint16_t* Alo = (const uint16_t*)(ws + OFF_ALO);
  const uint16_t* WlH = (const uint16_t*)(ws + OFF_WLHI);
  const uint16_t* WlL = (const uint16_t*)(ws + OFF_WLLO);
  const uint16_t* WsH = (const uint16_t*)(ws + OFF_WSHI);
  const uint16_t* WsL = (const uint16_t*)(ws + OFF_WSLO);
  float* partL = (float*)(ws + OFF_PARTL);
  float* partS = (float*)(ws + OFF_PARTS);
  float* c_l   = (float*)(ws + OFF_CL);
  float* h_f   = (float*)(ws + OFF_HF);
  float* c_s   = (float*)(ws + OFF_CS);
  float* p_acc = (float*)(ws + OFF_PACC);
  uint16_t* hHi  = (uint16_t*)(ws + OFF_HHI);
  uint16_t* hLo  = (uint16_t*)(ws + OFF_HLO);
  uint16_t* hsHi = (uint16_t*)(ws + OFF_HSHI);
  uint16_t* hsLo = (uint16_t*)(ws + OFF_HSLO);
  int* cnt  = (int*)(ws + OFF_CNT);
  int* cnt2 = (int*)(ws + OFF_CNT2);
  int* done = (int*)(ws + OFF_DONE);
  float* ppart = (float*)(ws + OFF_PPART);
  const float* rseq = (const float*)(ws + OFF_RSEQ);

  const int bid = blockIdx.x;
  const int lane = threadIdx.x;
  const int quad = lane >> 4, l16 = lane & 15;
  const bool isL = bid < 512;
  int D, s, wstride, hdim;
  const uint16_t *Wgh, *Wgl;
  if (isL) { D = bid >> 3; s = bid & 7; Wgh = WlH; Wgl = WlL; wstride = KL_; hdim = HL_; }
  else { int b2 = bid - 512; D = b2 >> 2; s = b2 & 3; Wgh = WsH; Wgl = WsL; wstride = KS_; hdim = HS_; }
  const int k0 = s * 192;
  const int cnt_target = (D < 16) ? 12 : 8;   // combined dtiles D<16 include 4 small producers

  // ---- stage weights into LDS once, in exact fragment-read order ----
  __shared__ bf16x8 sWhi[1536];   // [kk][nt][lane] -> 24 KB
  __shared__ bf16x8 sWlo[1536];   // 24 KB
#pragma unroll
  for (int kk = 0; kk < 6; ++kk)
#pragma unroll
    for (int nt = 0; nt < 4; ++nt) {
      int grow = nt * hdim + D * 16 + l16;       // gate nt, d = D*16+l16
      size_t wb = (size_t)grow * wstride + (size_t)(k0 + kk * 32 + quad * 8);
      sWhi[(kk * 4 + nt) * 64 + lane] = *(const bf16x8*)(Wgh + wb);
      sWlo[(kk * 4 + nt) * 64 + lane] = *(const bf16x8*)(Wgl + wb);
    }
  __syncthreads();

  float* partBase = isL ? (partL + (size_t)(D * 8 + s) * 4096)
                        : (partS + (size_t)(D * 4 + s) * 4096);

  for (int t = 0; t < L_; ++t) {
    // ---- wait for previous step's pointwise (all 64 dtiles) ----
    if (t > 0) {
      const int* dn = done + (t - 1) * 64;
      int gu = 0;
      for (;;) {
        int v = __hip_atomic_load(dn + lane, __ATOMIC_ACQUIRE, __HIP_MEMORY_SCOPE_AGENT);
        if (__ballot(v != 0) == ~0ull) break;
        __builtin_amdgcn_s_sleep(1);
        if (++gu > (1 << 20)) break;   // never a hang: break -> wrong answer, not timeout
      }
      __threadfence();
    }

    // ---- GEMM phase: 3-term split-bf16 MFMA, B-fragments from LDS ----
    const uint16_t* aEh = Ahi + (size_t)t * (B_ * E_);
    const uint16_t* aEl = Alo + (size_t)t * (B_ * E_);
    const uint16_t* aHh = isL ? (hHi + (size_t)(t & 1) * (B_ * HL_))
                              : (hsHi + (size_t)(t & 1) * (B_ * HS_));
    const uint16_t* aHl = isL ? (hLo + (size_t)(t & 1) * (B_ * HL_))
                              : (hsLo + (size_t)(t & 1) * (B_ * HS_));
    f32x4 acc[4][4];
#pragma unroll
    for (int mt = 0; mt < 4; ++mt)
#pragma unroll
      for (int nt = 0; nt < 4; ++nt) {
        acc[mt][nt][0] = 0.f; acc[mt][nt][1] = 0.f;
        acc[mt][nt][2] = 0.f; acc[mt][nt][3] = 0.f;
      }
    const int ko = quad * 8;
#pragma unroll
    for (int kk = 0; kk < 6; ++kk) {
      const int kbase = k0 + kk * 32;
      bf16x8 ah[4], al[4];
#pragma unroll
      for (int mt = 0; mt < 4; ++mt) {
        const int m = mt * 16 + l16;
        const uint16_t *ph, *pl;
        if (kbase < E_) { ph = aEh + m * E_ + kbase; pl = aEl + m * E_ + kbase; }
        else            { ph = aHh + m * hdim + (kbase - E_); pl = aHl + m * hdim + (kbase - E_); }
        ah[mt] = *(const bf16x8*)(ph + ko);
        al[mt] = *(const bf16x8*)(pl + ko);
      }
#pragma unroll
      for (int nt = 0; nt < 4; ++nt) {
        bf16x8 bh = sWhi[(kk * 4 + nt) * 64 + lane];
        bf16x8 bl = sWlo[(kk * 4 + nt) * 64 + lane];
#pragma unroll
        for (int mt = 0; mt < 4; ++mt) {
          acc[mt][nt] = __builtin_amdgcn_mfma_f32_16x16x32_bf16(ah[mt], bh, acc[mt][nt], 0, 0, 0);
          acc[mt][nt] = __builtin_amdgcn_mfma_f32_16x16x32_bf16(al[mt], bh, acc[mt][nt], 0, 0, 0);
          acc[mt][nt] = __builtin_amdgcn_mfma_f32_16x16x32_bf16(ah[mt], bl, acc[mt][nt], 0, 0, 0);
        }
      }
    }
    // partial store [rr][b]: rr = nt*16+l16, b = mt*16+quad*4+r (16 coalesced f32x4 stores)
#pragma unroll
    for (int nt = 0; nt < 4; ++nt)
#pragma unroll
      for (int mt = 0; mt < 4; ++mt)
        *(f32x4*)(partBase + (nt * 16 + l16) * 64 + mt * 16 + quad * 4) = acc[mt][nt];

    // ---- arrive (release partials) ----
    __threadfence();
    int* c1 = cnt + t * 64 + D;
    if (lane == 0)
      __hip_atomic_fetch_add(c1, 1, __ATOMIC_RELEASE, __HIP_MEMORY_SCOPE_AGENT);

    if (isL) {
      // ---- wait for all producers of this dtile ----
      int gu = 0;
      while (__hip_atomic_load(c1, __ATOMIC_ACQUIRE, __HIP_MEMORY_SCOPE_AGENT) < cnt_target) {
        __builtin_amdgcn_s_sleep(1);
        if (++gu > (1 << 20)) break;
      }
      __threadfence();

      // ---- pointwise for d_lo in {2s, 2s+1}; lane = batch ----
      const int nb = (t + 1) & 1;
      const int b = lane;
      float p0 = 0.f, p1 = 0.f;
#pragma unroll
      for (int dd2 = 0; dd2 < 2; ++dd2) {
        const int dlo = 2 * s + dd2;
        const int d = D * 16 + dlo;
        float g4[4];
#pragma unroll
        for (int gg = 0; gg < 4; ++gg) {
          float v = bihl[gg * HL_ + d] + bhhl[gg * HL_ + d];
#pragma unroll
          for (int sp = 0; sp < 8; ++sp)
            v += partL[(size_t)(D * 8 + sp) * 4096 + (gg * 16 + dlo) * 64 + b];
          g4[gg] = v;
        }
        float cprev = c_l[d * 64 + b];
        float cn = sigm(g4[1]) * cprev + sigm(g4[0]) * tanhf(g4[2]);
        float hn = sigm(g4[3]) * tanhf(cn);
        float hb, cb;
        if (D < 16) {   // d < 256: small cell + blend head
          float gs[4];
#pragma unroll
          for (int gg = 0; gg < 4; ++gg) {
            float v = bihs[gg * HS_ + d] + bhhs[gg * HS_ + d];
#pragma unroll
            for (int sp = 0; sp < 4; ++sp)
              v += partS[(size_t)(D * 4 + sp) * 4096 + (gg * 16 + dlo) * 64 + b];
            gs[gg] = v;
          }
          float csp = c_s[d * 64 + b];
          float cs_new = sigm(gs[1]) * csp + sigm(gs[0]) * tanhf(gs[2]);
          float hs_new = sigm(gs[3]) * tanhf(cs_new);
          c_s[d * 64 + b] = cs_new;
          uint16_t hi = f2bf(hs_new);
          hsHi[nb * (B_ * HS_) + b * HS_ + d] = hi;
          hsLo[nb * (B_ * HS_) + b * HS_ + d] = f2bf(hs_new - bf2f(hi));
          hb = hs_new; cb = cs_new;
        } else {        // d >= 256: tail = prev large h / new large c
          hb = h_f[d * 64 + b];
          cb = cn;
        }
        float r0v = rseq[(t * B_ + b) * 2 + 0];
        float r1v = rseq[(t * B_ + b) * 2 + 1];
        float hnext = r0v * hn + r1v * hb;
        float cnext = r0v * cn + r1v * cb;
        c_l[d * 64 + b] = cnext;
        h_f[d * 64 + b] = hnext;
        uint16_t hh = f2bf(hnext);
        hHi[nb * (B_ * HL_) + b * HL_ + d] = hh;
        hLo[nb * (B_ * HL_) + b * HL_ + d] = f2bf(hnext - bf2f(hh));
        out_h[((size_t)b * L_ + t) * HL_ + d] = hnext;
        p0 += hn * Wp[E_ + d] + cn * Wp[E_ + HL_ + d];
        p1 += hn * Wp[(E_ + 2 * HL_) + E_ + d] + cn * Wp[(E_ + 2 * HL_) + E_ + HL_ + d];
      }
      {
        float* pp = ppart + ((size_t)(D * 8 + s) * 64 + b) * 2;
        pp[0] = p0; pp[1] = p1;
      }
      __threadfence();
      int old = -1;
      if (lane == 0)
        old = __hip_atomic_fetch_add(cnt2 + t * 64 + D, 1, __ATOMIC_ACQ_REL, __HIP_MEMORY_SCOPE_AGENT);
      old = __shfl(old, 0);
      if (old == 7) {   // last finisher: deterministic p reduction + publish done
        __threadfence();
        float q0 = 0.f, q1 = 0.f;
#pragma unroll
        for (int sp = 0; sp < 8; ++sp) {
          const float* pq = ppart + ((size_t)(D * 8 + sp) * 64 + b) * 2;
          q0 += pq[0]; q1 += pq[1];
        }
        atomicAdd(&p_acc[(t * B_ + b) * 2 + 0], q0);
        atomicAdd(&p_acc[(t * B_ + b) * 2 + 1], q1);
        __threadfence();
        if (lane == 0)
          __hip_atomic_store(done + t * 64 + D, 1, __ATOMIC_RELEASE, __HIP_MEMORY_SCOPE_AGENT);
      }
    }
  }
}

// ---------------- final kernels ----------------

__global__ __launch_bounds__(256) void k_cls1(
    const float* __restrict__ h_f, const float* __restrict__ Wc1,
    const float* __restrict__ bc1, float* __restrict__ z1) {
  int idx = blockIdx.x * 256 + threadIdx.x;  // < 64*512
  int b = idx >> 9, j = idx & 511;
  float s = bc1[j];
  const float* wr = Wc1 + (size_t)j * HL_;
  for (int d = 0; d < HL_; ++d) s += fmaxf(h_f[d * 64 + b], 0.f) * wr[d];  // h_f is [d][b]
  z1[idx] = fmaxf(s, 0.f);
}

__global__ __launch_bounds__(64) void k_cls2(
    const float* __restrict__ z1, const float* __restrict__ Wc2,
    const float* __restrict__ bc2, float* __restrict__ out) {
  int b = blockIdx.x;
  int tid = threadIdx.x;
  __shared__ float sv[NC_];
  if (tid < NC_) {
    float s = bc2[tid];
    const float* zr = z1 + b * 512;
    const float* wr = Wc2 + tid * 512;
    for (int k = 0; k < 512; ++k) s += zr[k] * wr[k];
    sv[tid] = s;
  }
  __syncthreads();
  if (tid == 0) {
    float m = sv[0];
    for (int j = 1; j < NC_; ++j) m = fmaxf(m, sv[j]);
    float e[NC_], sum = 0.f;
    for (int j = 0; j < NC_; ++j) { e[j] = expf(sv[j] - m); sum += e[j]; }
    float inv = 1.0f / sum;
    for (int j = 0; j < NC_; ++j) out[b * NC_ + j] = e[j] * inv;
  }
}

__global__ __launch_bounds__(256) void k_pfinal(
    const float* __restrict__ p_acc, const float* __restrict__ Pe,
    const float* __restrict__ bp, float* __restrict__ out_p) {
  int idx = blockIdx.x * 256 + threadIdx.x;  // b*512+t
  int b = idx >> 9, t = idx & 511;
  int i2 = (t * B_ + b) * 2;
  float v0 = p_acc[i2 + 0] + Pe[i2 + 0] + bp[0];
  float v1 = p_acc[i2 + 1] + Pe[i2 + 1] + bp[1];
  float m = fmaxf(v0, v1);
  float e0 = expf(v0 - m), e1 = expf(v1 - m);
  float inv = 1.0f / (e0 + e1);
  out_p[(size_t)idx * 2 + 0] = e0 * inv;
  out_p[(size_t)idx * 2 + 1] = e1 * inv;
}

// ---------------- host ----------------
extern "C" void kernel_launch(void* const* d_in, const int* in_sizes, int n_in,
                              void* d_out, int out_size, void* d_ws, size_t ws_size,
                              hipStream_t stream) {
  const int*   x    = (const int*)d_in[0];
  const float* gum  = (const float*)d_in[1];
  const float* emb  = (const float*)d_in[2];
  const float* Wihl = (const float*)d_in[3];
  const float* Whhl = (const float*)d_in[4];
  const float* bihl = (const float*)d_in[5];
  const float* bhhl = (const float*)d_in[6];
  const float* Wihs = (const float*)d_in[7];
  const float* Whhs = (const float*)d_in[8];
  const float* bihs = (const float*)d_in[9];
  const float* bhhs = (const float*)d_in[10];
  const float* Wp   = (const float*)d_in[11];
  const float* bp   = (const float*)d_in[12];
  const float* Wc1  = (const float*)d_in[13];
  const float* bc1  = (const float*)d_in[14];
  const float* Wc2  = (const float*)d_in[15];
  const float* bc2  = (const float*)d_in[16];
  float* out = (float*)d_out;

  char* ws = (char*)d_ws;
  uint16_t* Ahi   = (uint16_t*)(ws + OFF_AHI);
  uint16_t* Alo   = (uint16_t*)(ws + OFF_ALO);
  uint16_t* Wl_hi = (uint16_t*)(ws + OFF_WLHI);
  uint16_t* Wl_lo = (uint16_t*)(ws + OFF_WLLO);
  uint16_t* Ws_hi = (uint16_t*)(ws + OFF_WSHI);
  uint16_t* Ws_lo = (uint16_t*)(ws + OFF_WSLO);
  float*    h_f   = (float*)(ws + OFF_HF);
  float*    p_acc = (float*)(ws + OFF_PACC);
  float*    Pe    = (float*)(ws + OFF_PE);
  float*    rseq  = (float*)(ws + OFF_RSEQ);
  float*    z1    = (float*)(ws + OFF_Z1);

  float* out_logits = out;                          // 320
  float* out_h      = out + 320;                    // [B][L][HL]
  float* out_p      = out + 320 + (size_t)B_ * L_ * HL_;  // [B][L][2]

  // ---- setup ----
  {
    int n = 4096 * KL_ + 1024 * KS_;  // 7,077,888
    k_convw<<<(n + 255) / 256, 256, 0, stream>>>(Wihl, Whhl, Wihs, Whhs,
                                                 Wl_hi, Wl_lo, Ws_hi, Ws_lo);
  }
  k_embed<<<(L_ * B_ * E_) / 256, 256, 0, stream>>>(x, emb, Ahi, Alo);
  {
    int nwords = (int)((OFF_STATE_END - OFF_CL) / 4);  // 540,672 (state + sync counters)
    k_zero<<<(nwords + 255) / 256, 256, 0, stream>>>((uint32_t*)(ws + OFF_CL), nwords);
  }
  k_rseq<<<(L_ * B_) / 256, 256, 0, stream>>>(gum, rseq);
  k_pe<<<(L_ * B_) / 256, 256, 0, stream>>>(x, emb, Wp, Pe);

  // ---- persistent scan: one kernel, 512 steps, flag-synchronized ----
  // 576 blocks x 64 thr, 48KB LDS/block -> 3 blocks/CU -> 768 resident slots >= 576.
  k_scan<<<576, 64, 0, stream>>>(ws, bihl, bhhl, bihs, bhhs, Wp, out_h);

  // ---- epilogue ----
  k_cls1<<<(B_ * 512) / 256, 256, 0, stream>>>(h_f, Wc1, bc1, z1);
  k_cls2<<<B_, 64, 0, stream>>>(z1, Wc2, bc2, out_logits);
  k_pfinal<<<(B_ * L_) / 256, 256, 0, stream>>>(p_acc, Pe, bp, out_p);
}

// Round 2
// 25034.999 us; speedup vs baseline: 4.8984x; 4.8984x over previous
//
#include <hip/hip_runtime.h>
#include <stdint.h>
#include <stddef.h>

// ---------------- problem constants ----------------
#define B_   64
#define L_   512
#define E_   512
#define HL_  1024
#define HS_  256
#define NC_  5
#define KL_  (E_ + HL_)   // 1536
#define KS_  (E_ + HS_)   // 768

// ---------------- workspace layout (bytes) ----------------
#define OFF_AHI   0ull            // [L][B][E] u16      33,554,432
#define OFF_ALO   33554432ull     //                    33,554,432
#define OFF_WLHI  67108864ull     // [4096][1536] u16   12,582,912
#define OFF_WLLO  79691776ull     //                    12,582,912
#define OFF_WSHI  92274688ull     // [1024][768]  u16    1,572,864
#define OFF_WSLO  93847552ull     //                     1,572,864
// ---- state block (zeroed every launch) ----
#define OFF_CL    104857600ull    // [1024 d][64 b] f32   262,144
#define OFF_HF    105119744ull    // [1024 d][64 b] f32   262,144
#define OFF_CS    105381888ull    // [256 d][64 b]  f32    65,536
#define OFF_PACC  105447424ull    // [512 t][64 b][2] f32 262,144
#define OFF_HHI   105709568ull    // [2 buf][64 b][1024 d] u16 262,144
#define OFF_HLO   105971712ull    //                      262,144
#define OFF_HSHI  106233856ull    // [2 buf][64 b][256 d] u16  65,536
#define OFF_HSLO  106299392ull    //                       65,536
#define OFF_STATE_END 106364928ull
// ---- non-zeroed scratch ----
#define OFF_PE    107020288ull    // [512 t][64 b][2] f32 262,144
#define OFF_RSEQ  107282432ull    // [512 t][64 b][2] f32 262,144
#define OFF_Z1    107544576ull    // [64][512] f32        131,072
// end = 107,675,648 (same footprint as the known-good round-0 layout)

typedef __attribute__((ext_vector_type(8))) short bf16x8;   // 8 bf16 in 4 VGPRs
typedef __attribute__((ext_vector_type(4))) float f32x4;

__device__ __forceinline__ uint16_t f2bf(float f) {
  union { float f; uint32_t u; } v; v.f = f;
  uint32_t r = v.u + 0x7FFFu + ((v.u >> 16) & 1u);
  return (uint16_t)(r >> 16);
}
__device__ __forceinline__ float bf2f(uint16_t h) {
  union { uint32_t u; float f; } v; v.u = ((uint32_t)h) << 16; return v.f;
}
__device__ __forceinline__ float sigm(float x) { return 1.0f / (1.0f + expf(-x)); }

// ---------------- setup kernels ----------------

__global__ __launch_bounds__(256) void k_convw(
    const float* __restrict__ Wihl, const float* __restrict__ Whhl,
    const float* __restrict__ Wihs, const float* __restrict__ Whhs,
    uint16_t* __restrict__ Wl_hi, uint16_t* __restrict__ Wl_lo,
    uint16_t* __restrict__ Ws_hi, uint16_t* __restrict__ Ws_lo) {
  const int N1 = 4096 * KL_;
  const int N2 = 1024 * KS_;
  int idx = blockIdx.x * 256 + threadIdx.x;
  if (idx < N1) {
    int row = idx / KL_, k = idx - row * KL_;
    float v = (k < E_) ? Wihl[row * E_ + k] : Whhl[row * HL_ + (k - E_)];
    uint16_t hi = f2bf(v);
    Wl_hi[idx] = hi;
    Wl_lo[idx] = f2bf(v - bf2f(hi));
  } else if (idx < N1 + N2) {
    int j = idx - N1;
    int row = j / KS_, k = j - row * KS_;
    float v = (k < E_) ? Wihs[row * E_ + k] : Whhs[row * HS_ + (k - E_)];
    uint16_t hi = f2bf(v);
    Ws_hi[j] = hi;
    Ws_lo[j] = f2bf(v - bf2f(hi));
  }
}

__global__ __launch_bounds__(256) void k_embed(
    const int* __restrict__ x, const float* __restrict__ emb,
    uint16_t* __restrict__ Ahi, uint16_t* __restrict__ Alo) {
  int idx = blockIdx.x * 256 + threadIdx.x;
  int t = idx >> 15;
  int rem = idx & 32767;
  int b = rem >> 9;
  int k = rem & 511;
  int tok = x[b * L_ + t];
  float v = emb[(size_t)tok * E_ + k];
  uint16_t hi = f2bf(v);
  Ahi[idx] = hi;
  Alo[idx] = f2bf(v - bf2f(hi));
}

__global__ __launch_bounds__(256) void k_zero(uint32_t* __restrict__ p, int nwords) {
  int idx = blockIdx.x * 256 + threadIdx.x;
  if (idx < nwords) p[idx] = 0u;
}

__global__ __launch_bounds__(256) void k_rseq(
    const float* __restrict__ gum, float* __restrict__ rseq) {
  int idx = blockIdx.x * 256 + threadIdx.x;       // t*64+b
  int t = idx >> 6, b = idx & 63;
  float u0 = gum[(b * L_ + t) * 2 + 0];
  float u1 = gum[(b * L_ + t) * 2 + 1];
  float g0 = -logf(-logf(u0));
  float g1 = -logf(-logf(u1));
  float m = fmaxf(g0, g1);
  float e0 = expf(g0 - m), e1 = expf(g1 - m);
  float inv = 1.0f / (e0 + e1);
  rseq[idx * 2 + 0] = e0 * inv;
  rseq[idx * 2 + 1] = e1 * inv;
}

__global__ __launch_bounds__(256) void k_pe(
    const int* __restrict__ x, const float* __restrict__ emb,
    const float* __restrict__ Wp, float* __restrict__ Pe) {
  int idx = blockIdx.x * 256 + threadIdx.x;       // t*64+b
  int t = idx >> 6, b = idx & 63;
  int tok = x[b * L_ + t];
  const float* row = emb + (size_t)tok * E_;
  float a0 = 0.f, a1 = 0.f;
  for (int k = 0; k < E_; ++k) {
    float e = row[k];
    a0 += e * Wp[k];
    a1 += e * Wp[(E_ + 2 * HL_) + k];
  }
  Pe[idx * 2 + 0] = a0;
  Pe[idx * 2 + 1] = a1;
}

// ---------------- per-step fused kernel ----------------
// 64 blocks x 256 threads (4 waves). Block D owns d-tile D (16 d's) of the
// large cell: 64 rows = 4 gates x 16 d's, full K=1536 split across the 4
// waves (384 each). Waves reduce through LDS (cheap intra-block sync) —
// no global partial buffer, no second kernel. Blocks D<16 additionally
// compute the small cell's matching 64 rows (K=768, 192/wave).
// The whole pointwise (LSTM gates, blend, h/c update, out_h, p-partials)
// is block-local. Cross-step ordering = kernel boundary (proven cheap).
// h/hs are double-buffered bf16 hi/lo to avoid intra-step WAR between this
// block's writes and other blocks' GEMM reads.
__global__ __launch_bounds__(256, 1) void k_step(
    char* __restrict__ ws,
    const float* __restrict__ bihl, const float* __restrict__ bhhl,
    const float* __restrict__ bihs, const float* __restrict__ bhhs,
    const float* __restrict__ Wp, float* __restrict__ out_h, int t) {
  const uint16_t* Ahi = (const uint16_t*)(ws + OFF_AHI);
  const uint16_t* Alo = (const uint16_t*)(ws + OFF_ALO);
  const uint16_t* WlH = (const uint16_t*)(ws + OFF_WLHI);
  const uint16_t* WlL = (const uint16_t*)(ws + OFF_WLLO);
  const uint16_t* WsH = (const uint16_t*)(ws + OFF_WSHI);
  const uint16_t* WsL = (const uint16_t*)(ws + OFF_WSLO);
  float* c_l   = (float*)(ws + OFF_CL);
  float* h_f   = (float*)(ws + OFF_HF);
  float* c_s   = (float*)(ws + OFF_CS);
  float* p_acc = (float*)(ws + OFF_PACC);
  uint16_t* hHi  = (uint16_t*)(ws + OFF_HHI);
  uint16_t* hLo  = (uint16_t*)(ws + OFF_HLO);
  uint16_t* hsHi = (uint16_t*)(ws + OFF_HSHI);
  uint16_t* hsLo = (uint16_t*)(ws + OFF_HSLO);
  const float* rseq = (const float*)(ws + OFF_RSEQ);

  const int D = blockIdx.x;
  const int tid = threadIdx.x;
  const int w = tid >> 6;
  const int lane = tid & 63;
  const int quad = lane >> 4, l16 = lane & 15;

  // pad 64->72 words: write stride 72 gives 4-way LDS bank aliasing (vs 16-way
  // unpadded); 72*4B keeps 16B alignment for f32x4 stores. 73.7 KB.
  __shared__ float red[4][64][72];

  const uint16_t* aEh = Ahi + (size_t)t * (B_ * E_);
  const uint16_t* aEl = Alo + (size_t)t * (B_ * E_);
  const uint16_t* hH  = hHi + (size_t)(t & 1) * (B_ * HL_);
  const uint16_t* hLm = hLo + (size_t)(t & 1) * (B_ * HL_);
  const uint16_t* sH  = hsHi + (size_t)(t & 1) * (B_ * HS_);
  const uint16_t* sLm = hsLo + (size_t)(t & 1) * (B_ * HS_);
  const int ko = quad * 8;

  // ---- large-cell GEMM: rows = gate*HL + D*16 + l16, K chunk = w*384..+384 ----
  {
    f32x4 acc[4][4];
#pragma unroll
    for (int mt = 0; mt < 4; ++mt)
#pragma unroll
      for (int nt = 0; nt < 4; ++nt) {
        acc[mt][nt][0] = 0.f; acc[mt][nt][1] = 0.f;
        acc[mt][nt][2] = 0.f; acc[mt][nt][3] = 0.f;
      }
#pragma unroll
    for (int kk = 0; kk < 12; ++kk) {
      const int kbase = w * 384 + kk * 32;
      bf16x8 ah[4], al[4];
#pragma unroll
      for (int mt = 0; mt < 4; ++mt) {
        const int m = mt * 16 + l16;
        const uint16_t *ph, *pl;
        if (kbase < E_) { ph = aEh + m * E_ + kbase; pl = aEl + m * E_ + kbase; }
        else            { ph = hH + m * HL_ + (kbase - E_); pl = hLm + m * HL_ + (kbase - E_); }
        ah[mt] = *(const bf16x8*)(ph + ko);
        al[mt] = *(const bf16x8*)(pl + ko);
      }
#pragma unroll
      for (int nt = 0; nt < 4; ++nt) {
        const size_t wb = (size_t)(nt * HL_ + D * 16 + l16) * KL_ + (size_t)(kbase + ko);
        bf16x8 bh = *(const bf16x8*)(WlH + wb);
        bf16x8 bl = *(const bf16x8*)(WlL + wb);
#pragma unroll
        for (int mt = 0; mt < 4; ++mt) {
          acc[mt][nt] = __builtin_amdgcn_mfma_f32_16x16x32_bf16(ah[mt], bh, acc[mt][nt], 0, 0, 0);
          acc[mt][nt] = __builtin_amdgcn_mfma_f32_16x16x32_bf16(al[mt], bh, acc[mt][nt], 0, 0, 0);
          acc[mt][nt] = __builtin_amdgcn_mfma_f32_16x16x32_bf16(ah[mt], bl, acc[mt][nt], 0, 0, 0);
        }
      }
    }
    // D frag: batch m = mt*16+quad*4+r, row rr = nt*16+l16
#pragma unroll
    for (int nt = 0; nt < 4; ++nt)
#pragma unroll
      for (int mt = 0; mt < 4; ++mt)
        *(f32x4*)&red[w][nt * 16 + l16][mt * 16 + quad * 4] = acc[mt][nt];
  }
  __syncthreads();

  // ---- per-thread gate sums (thread -> b = tid&63, dd = tid>>6) ----
  const int b = tid & 63;
  const int dd = tid >> 6;
  float gl[4][4];
#pragma unroll
  for (int i = 0; i < 4; ++i) {
    const int dl = dd + 4 * i;
    const int d = D * 16 + dl;
#pragma unroll
    for (int g = 0; g < 4; ++g) {
      const int row = g * HL_ + d;
      float v = bihl[row] + bhhl[row];
#pragma unroll
      for (int w4 = 0; w4 < 4; ++w4) v += red[w4][g * 16 + dl][b];
      gl[i][g] = v;
    }
  }
  __syncthreads();   // red about to be reused by the small cell

  // ---- small-cell GEMM + sums (blocks D<16 only; uniform per block) ----
  float gs[4][4];
  const bool hasS = (D < 16);
  if (hasS) {
    f32x4 acc[4][4];
#pragma unroll
    for (int mt = 0; mt < 4; ++mt)
#pragma unroll
      for (int nt = 0; nt < 4; ++nt) {
        acc[mt][nt][0] = 0.f; acc[mt][nt][1] = 0.f;
        acc[mt][nt][2] = 0.f; acc[mt][nt][3] = 0.f;
      }
#pragma unroll
    for (int kk = 0; kk < 6; ++kk) {
      const int kbase = w * 192 + kk * 32;
      bf16x8 ah[4], al[4];
#pragma unroll
      for (int mt = 0; mt < 4; ++mt) {
        const int m = mt * 16 + l16;
        const uint16_t *ph, *pl;
        if (kbase < E_) { ph = aEh + m * E_ + kbase; pl = aEl + m * E_ + kbase; }
        else            { ph = sH + m * HS_ + (kbase - E_); pl = sLm + m * HS_ + (kbase - E_); }
        ah[mt] = *(const bf16x8*)(ph + ko);
        al[mt] = *(const bf16x8*)(pl + ko);
      }
#pragma unroll
      for (int nt = 0; nt < 4; ++nt) {
        const size_t wb = (size_t)(nt * HS_ + D * 16 + l16) * KS_ + (size_t)(kbase + ko);
        bf16x8 bh = *(const bf16x8*)(WsH + wb);
        bf16x8 bl = *(const bf16x8*)(WsL + wb);
#pragma unroll
        for (int mt = 0; mt < 4; ++mt) {
          acc[mt][nt] = __builtin_amdgcn_mfma_f32_16x16x32_bf16(ah[mt], bh, acc[mt][nt], 0, 0, 0);
          acc[mt][nt] = __builtin_amdgcn_mfma_f32_16x16x32_bf16(al[mt], bh, acc[mt][nt], 0, 0, 0);
          acc[mt][nt] = __builtin_amdgcn_mfma_f32_16x16x32_bf16(ah[mt], bl, acc[mt][nt], 0, 0, 0);
        }
      }
    }
#pragma unroll
    for (int nt = 0; nt < 4; ++nt)
#pragma unroll
      for (int mt = 0; mt < 4; ++mt)
        *(f32x4*)&red[w][nt * 16 + l16][mt * 16 + quad * 4] = acc[mt][nt];
    __syncthreads();
#pragma unroll
    for (int i = 0; i < 4; ++i) {
      const int dl = dd + 4 * i;
      const int d = D * 16 + dl;
#pragma unroll
      for (int g = 0; g < 4; ++g) {
        const int row = g * HS_ + d;
        float v = bihs[row] + bhhs[row];
#pragma unroll
        for (int w4 = 0; w4 < 4; ++w4) v += red[w4][g * 16 + dl][b];
        gs[i][g] = v;
      }
    }
  }

  // ---- pointwise: gates -> states -> blend -> writes (all block-local) ----
  const float r0v = rseq[(t * B_ + b) * 2 + 0];
  const float r1v = rseq[(t * B_ + b) * 2 + 1];
  const int nb = (t + 1) & 1;
  float p0 = 0.f, p1 = 0.f;
#pragma unroll
  for (int i = 0; i < 4; ++i) {
    const int dl = dd + 4 * i;
    const int d = D * 16 + dl;
    const float cprev = c_l[d * 64 + b];
    const float cn = sigm(gl[i][1]) * cprev + sigm(gl[i][0]) * tanhf(gl[i][2]);
    const float hn = sigm(gl[i][3]) * tanhf(cn);
    float hb, cb;
    if (hasS) {
      const float csp = c_s[d * 64 + b];
      const float cs_new = sigm(gs[i][1]) * csp + sigm(gs[i][0]) * tanhf(gs[i][2]);
      const float hs_new = sigm(gs[i][3]) * tanhf(cs_new);
      c_s[d * 64 + b] = cs_new;
      const uint16_t shi = f2bf(hs_new);
      hsHi[nb * (B_ * HS_) + b * HS_ + d] = shi;
      hsLo[nb * (B_ * HS_) + b * HS_ + d] = f2bf(hs_new - bf2f(shi));
      hb = hs_new; cb = cs_new;
    } else {
      hb = h_f[d * 64 + b];   // prev large h (read before write below)
      cb = cn;
    }
    const float hnext = r0v * hn + r1v * hb;
    const float cnext = r0v * cn + r1v * cb;
    c_l[d * 64 + b] = cnext;
    h_f[d * 64 + b] = hnext;
    const uint16_t hh = f2bf(hnext);
    hHi[nb * (B_ * HL_) + b * HL_ + d] = hh;
    hLo[nb * (B_ * HL_) + b * HL_ + d] = f2bf(hnext - bf2f(hh));
    out_h[((size_t)b * L_ + t) * HL_ + d] = hnext;
    p0 += hn * Wp[E_ + d] + cn * Wp[E_ + HL_ + d];
    p1 += hn * Wp[(E_ + 2 * HL_) + E_ + d] + cn * Wp[(E_ + 2 * HL_) + E_ + HL_ + d];
  }

  // ---- p-partial reduce across dd-groups, one atomic pair per (block, b) ----
  __syncthreads();
  float* sp = &red[0][0][0];
  sp[tid] = p0;
  sp[256 + tid] = p1;
  __syncthreads();
  if (tid < 64) {
    float q0 = sp[tid] + sp[64 + tid] + sp[128 + tid] + sp[192 + tid];
    float q1 = sp[256 + tid] + sp[320 + tid] + sp[384 + tid] + sp[448 + tid];
    atomicAdd(&p_acc[(t * B_ + tid) * 2 + 0], q0);
    atomicAdd(&p_acc[(t * B_ + tid) * 2 + 1], q1);
  }
}

// ---------------- final kernels ----------------

__global__ __launch_bounds__(256) void k_cls1(
    const float* __restrict__ h_f, const float* __restrict__ Wc1,
    const float* __restrict__ bc1, float* __restrict__ z1) {
  int idx = blockIdx.x * 256 + threadIdx.x;  // < 64*512
  int b = idx >> 9, j = idx & 511;
  float s = bc1[j];
  const float* wr = Wc1 + (size_t)j * HL_;
  for (int d = 0; d < HL_; ++d) s += fmaxf(h_f[d * 64 + b], 0.f) * wr[d];  // h_f is [d][b]
  z1[idx] = fmaxf(s, 0.f);
}

__global__ __launch_bounds__(64) void k_cls2(
    const float* __restrict__ z1, const float* __restrict__ Wc2,
    const float* __restrict__ bc2, float* __restrict__ out) {
  int b = blockIdx.x;
  int tid = threadIdx.x;
  __shared__ float sv[NC_];
  if (tid < NC_) {
    float s = bc2[tid];
    const float* zr = z1 + b * 512;
    const float* wr = Wc2 + tid * 512;
    for (int k = 0; k < 512; ++k) s += zr[k] * wr[k];
    sv[tid] = s;
  }
  __syncthreads();
  if (tid == 0) {
    float m = sv[0];
    for (int j = 1; j < NC_; ++j) m = fmaxf(m, sv[j]);
    float e[NC_], sum = 0.f;
    for (int j = 0; j < NC_; ++j) { e[j] = expf(sv[j] - m); sum += e[j]; }
    float inv = 1.0f / sum;
    for (int j = 0; j < NC_; ++j) out[b * NC_ + j] = e[j] * inv;
  }
}

__global__ __launch_bounds__(256) void k_pfinal(
    const float* __restrict__ p_acc, const float* __restrict__ Pe,
    const float* __restrict__ bp, float* __restrict__ out_p) {
  int idx = blockIdx.x * 256 + threadIdx.x;  // b*512+t
  int b = idx >> 9, t = idx & 511;
  int i2 = (t * B_ + b) * 2;
  float v0 = p_acc[i2 + 0] + Pe[i2 + 0] + bp[0];
  float v1 = p_acc[i2 + 1] + Pe[i2 + 1] + bp[1];
  float m = fmaxf(v0, v1);
  float e0 = expf(v0 - m), e1 = expf(v1 - m);
  float inv = 1.0f / (e0 + e1);
  out_p[(size_t)idx * 2 + 0] = e0 * inv;
  out_p[(size_t)idx * 2 + 1] = e1 * inv;
}

// ---------------- host ----------------
extern "C" void kernel_launch(void* const* d_in, const int* in_sizes, int n_in,
                              void* d_out, int out_size, void* d_ws, size_t ws_size,
                              hipStream_t stream) {
  const int*   x    = (const int*)d_in[0];
  const float* gum  = (const float*)d_in[1];
  const float* emb  = (const float*)d_in[2];
  const float* Wihl = (const float*)d_in[3];
  const float* Whhl = (const float*)d_in[4];
  const float* bihl = (const float*)d_in[5];
  const float* bhhl = (const float*)d_in[6];
  const float* Wihs = (const float*)d_in[7];
  const float* Whhs = (const float*)d_in[8];
  const float* bihs = (const float*)d_in[9];
  const float* bhhs = (const float*)d_in[10];
  const float* Wp   = (const float*)d_in[11];
  const float* bp   = (const float*)d_in[12];
  const float* Wc1  = (const float*)d_in[13];
  const float* bc1  = (const float*)d_in[14];
  const float* Wc2  = (const float*)d_in[15];
  const float* bc2  = (const float*)d_in[16];
  float* out = (float*)d_out;

  char* ws = (char*)d_ws;
  uint16_t* Ahi   = (uint16_t*)(ws + OFF_AHI);
  uint16_t* Alo   = (uint16_t*)(ws + OFF_ALO);
  uint16_t* Wl_hi = (uint16_t*)(ws + OFF_WLHI);
  uint16_t* Wl_lo = (uint16_t*)(ws + OFF_WLLO);
  uint16_t* Ws_hi = (uint16_t*)(ws + OFF_WSHI);
  uint16_t* Ws_lo = (uint16_t*)(ws + OFF_WSLO);
  float*    h_f   = (float*)(ws + OFF_HF);
  float*    p_acc = (float*)(ws + OFF_PACC);
  float*    Pe    = (float*)(ws + OFF_PE);
  float*    rseq  = (float*)(ws + OFF_RSEQ);
  float*    z1    = (float*)(ws + OFF_Z1);

  float* out_logits = out;                          // 320
  float* out_h      = out + 320;                    // [B][L][HL]
  float* out_p      = out + 320 + (size_t)B_ * L_ * HL_;  // [B][L][2]

  // ---- setup ----
  {
    int n = 4096 * KL_ + 1024 * KS_;  // 7,077,888
    k_convw<<<(n + 255) / 256, 256, 0, stream>>>(Wihl, Whhl, Wihs, Whhs,
                                                 Wl_hi, Wl_lo, Ws_hi, Ws_lo);
  }
  k_embed<<<(L_ * B_ * E_) / 256, 256, 0, stream>>>(x, emb, Ahi, Alo);
  {
    int nwords = (int)((OFF_STATE_END - OFF_CL) / 4);  // state block words
    k_zero<<<(nwords + 255) / 256, 256, 0, stream>>>((uint32_t*)(ws + OFF_CL), nwords);
  }
  k_rseq<<<(L_ * B_) / 256, 256, 0, stream>>>(gum, rseq);
  k_pe<<<(L_ * B_) / 256, 256, 0, stream>>>(x, emb, Wp, Pe);

  // ---- sequential scan: ONE fused kernel per step (kernel boundary = sync) ----
  for (int t = 0; t < L_; ++t) {
    k_step<<<64, 256, 0, stream>>>(ws, bihl, bhhl, bihs, bhhs, Wp, out_h, t);
  }

  // ---- epilogue ----
  k_cls1<<<(B_ * 512) / 256, 256, 0, stream>>>(h_f, Wc1, bc1, z1);
  k_cls2<<<B_, 64, 0, stream>>>(z1, Wc2, bc2, out_logits);
  k_pfinal<<<(B_ * L_) / 256, 256, 0, stream>>>(p_acc, Pe, bp, out_p);
}

// Round 3
// 12127.390 us; speedup vs baseline: 10.1120x; 2.0643x over previous
//
#include <hip/hip_runtime.h>
#include <stdint.h>
#include <stddef.h>

// ---------------- problem constants ----------------
#define B_   64
#define L_   512
#define E_   512
#define HL_  1024
#define HS_  256
#define NC_  5
#define KL_  (E_ + HL_)   // 1536  concat K for large cell
#define KS_  (E_ + HS_)   // 768   concat K for small cell
#define ROWS_L_ 4096      // 4*HL
#define ROWS_S_ 1024      // 4*HS
#define ROWS_TOT_ 5120
#define SL_  8            // K-slices large (192 each = 6 ksteps of 32)
#define SS_  4            // K-slices small (192 each)

typedef __attribute__((ext_vector_type(8))) short bf16x8;   // 8 bf16 in 4 VGPRs
typedef __attribute__((ext_vector_type(4))) float f32x4;
typedef __attribute__((ext_vector_type(4))) short s16x4;

__device__ __forceinline__ uint16_t f2bf(float f) {
  union { float f; uint32_t u; } v; v.f = f;
  uint32_t r = v.u + 0x7FFFu + ((v.u >> 16) & 1u);
  return (uint16_t)(r >> 16);
}
__device__ __forceinline__ float bf2f(uint16_t h) {
  union { uint32_t u; float f; } v; v.u = ((uint32_t)h) << 16; return v.f;
}
__device__ __forceinline__ float sigm(float x) { return 1.0f / (1.0f + expf(-x)); }

// ---------------- setup kernels ----------------

// Build bf16 hi/lo concatenated weights: Wl[4096][1536] = [W_ih_l | W_hh_l],
// Ws[1024][768] = [W_ih_s | W_hh_s].  lo = round(v - hi) captures next 8 bits.
__global__ __launch_bounds__(256) void k_convw(
    const float* __restrict__ Wihl, const float* __restrict__ Whhl,
    const float* __restrict__ Wihs, const float* __restrict__ Whhs,
    uint16_t* __restrict__ Wl_hi, uint16_t* __restrict__ Wl_lo,
    uint16_t* __restrict__ Ws_hi, uint16_t* __restrict__ Ws_lo) {
  const int N1 = ROWS_L_ * KL_;          // 6291456
  const int N2 = ROWS_S_ * KS_;          // 786432
  int idx = blockIdx.x * 256 + threadIdx.x;
  if (idx < N1) {
    int row = idx / KL_, k = idx - row * KL_;
    float v = (k < E_) ? Wihl[row * E_ + k] : Whhl[row * HL_ + (k - E_)];
    uint16_t hi = f2bf(v);
    Wl_hi[idx] = hi;
    Wl_lo[idx] = f2bf(v - bf2f(hi));
  } else if (idx < N1 + N2) {
    int j = idx - N1;
    int row = j / KS_, k = j - row * KS_;
    float v = (k < E_) ? Wihs[row * E_ + k] : Whhs[row * HS_ + (k - E_)];
    uint16_t hi = f2bf(v);
    Ws_hi[j] = hi;
    Ws_lo[j] = f2bf(v - bf2f(hi));
  }
}

// Gather embedding rows into bf16 hi/lo: A[t][b][k]
__global__ __launch_bounds__(256) void k_embed(
    const int* __restrict__ x, const float* __restrict__ emb,
    uint16_t* __restrict__ Ahi, uint16_t* __restrict__ Alo) {
  int idx = blockIdx.x * 256 + threadIdx.x;       // < L*B*E = 16.7M
  int t = idx >> 15;                               // /(B*E)
  int rem = idx & 32767;
  int b = rem >> 9;                                // /E
  int k = rem & 511;
  int tok = x[b * L_ + t];
  float v = emb[(size_t)tok * E_ + k];
  uint16_t hi = f2bf(v);
  Ahi[idx] = hi;
  Alo[idx] = f2bf(v - bf2f(hi));
}

// Zero the state block — ws is poisoned 0xAA.
__global__ __launch_bounds__(256) void k_zero(uint32_t* __restrict__ p, int nwords) {
  int idx = blockIdx.x * 256 + threadIdx.x;
  if (idx < nwords) p[idx] = 0u;
}

// r_seq[t][b][2] = softmax(-log(-log(u)))   (tau = 1; p_t faithfully unused)
__global__ __launch_bounds__(256) void k_rseq(
    const float* __restrict__ gum, float* __restrict__ rseq) {
  int idx = blockIdx.x * 256 + threadIdx.x;       // t*64+b
  int t = idx >> 6, b = idx & 63;
  float u0 = gum[(b * L_ + t) * 2 + 0];
  float u1 = gum[(b * L_ + t) * 2 + 1];
  float g0 = -logf(-logf(u0));
  float g1 = -logf(-logf(u1));
  float m = fmaxf(g0, g1);
  float e0 = expf(g0 - m), e1 = expf(g1 - m);
  float inv = 1.0f / (e0 + e1);
  rseq[idx * 2 + 0] = e0 * inv;
  rseq[idx * 2 + 1] = e1 * inv;
}

// Pe[t][b][j] = e_t[b] . W_p[j][0:512]  computed from fp32 emb (exact)
__global__ __launch_bounds__(256) void k_pe(
    const int* __restrict__ x, const float* __restrict__ emb,
    const float* __restrict__ Wp, float* __restrict__ Pe) {
  int idx = blockIdx.x * 256 + threadIdx.x;       // t*64+b
  int t = idx >> 6, b = idx & 63;
  int tok = x[b * L_ + t];
  const float* row = emb + (size_t)tok * E_;
  float a0 = 0.f, a1 = 0.f;
  for (int k = 0; k < E_; ++k) {
    float e = row[k];
    a0 += e * Wp[k];
    a1 += e * Wp[(E_ + 2 * HL_) + k];
  }
  Pe[idx * 2 + 0] = a0;
  Pe[idx * 2 + 1] = a1;
}

// ---------------- per-step kernel A: K-sliced 3-term split-bf16 MFMA GEMM ----
// (verbatim from the proven 10.68 ms version)
// acc += Ahi.Whi + Alo.Whi + Ahi.Wlo   (fp32-accurate to ~2^-16 rel)
// blocks 0..511  : large cell, rowtile rt=bid>>3 (64 rows), slice s=bid&7
// blocks 512..575: small cell, rowtile rt (64 rows), slice s=bid&3
__global__ __launch_bounds__(64) void k_step_gemm(
    const uint16_t* __restrict__ Ahi, const uint16_t* __restrict__ Alo,
    const uint16_t* __restrict__ h_hi, const uint16_t* __restrict__ h_lo,
    const uint16_t* __restrict__ hs_hi, const uint16_t* __restrict__ hs_lo,
    const uint16_t* __restrict__ Wl_hi, const uint16_t* __restrict__ Wl_lo,
    const uint16_t* __restrict__ Ws_hi, const uint16_t* __restrict__ Ws_lo,
    float* __restrict__ partial, int t) {
  int bid = blockIdx.x;
  int lane = threadIdx.x;
  int quad = lane >> 4, l16 = lane & 15;
  const uint16_t* actE_hi = Ahi + (size_t)t * (B_ * E_);
  const uint16_t* actE_lo = Alo + (size_t)t * (B_ * E_);
  const uint16_t *actH_hi, *actH_lo, *W_hi, *W_lo;
  int r0, s, wstride, hstride, rbase;
  if (bid < 512) {
    int rt = bid >> 3; s = bid & 7;
    r0 = rt * 64; W_hi = Wl_hi; W_lo = Wl_lo; wstride = KL_;
    actH_hi = h_hi; actH_lo = h_lo; hstride = HL_; rbase = 0;
  } else {
    int b2 = bid - 512;
    int rt = b2 >> 2; s = b2 & 3;
    r0 = rt * 64; W_hi = Ws_hi; W_lo = Ws_lo; wstride = KS_;
    actH_hi = hs_hi; actH_lo = hs_lo; hstride = HS_; rbase = ROWS_L_;
  }
  int k0 = s * 192;

  f32x4 acc[4][4];
#pragma unroll
  for (int mt = 0; mt < 4; ++mt)
#pragma unroll
    for (int nt = 0; nt < 4; ++nt) {
      acc[mt][nt][0] = 0.f; acc[mt][nt][1] = 0.f;
      acc[mt][nt][2] = 0.f; acc[mt][nt][3] = 0.f;
    }

  int ko = quad * 8;
#pragma unroll
  for (int kk = 0; kk < 6; ++kk) {
    int kbase = k0 + kk * 32;
    bf16x8 a_hi[4], a_lo[4], b_hi[4], b_lo[4];
#pragma unroll
    for (int mt = 0; mt < 4; ++mt) {
      int m = mt * 16 + l16;  // batch
      const uint16_t* phi;
      const uint16_t* plo;
      if (kbase < E_) {
        phi = actE_hi + m * E_ + kbase;
        plo = actE_lo + m * E_ + kbase;
      } else {
        phi = actH_hi + m * hstride + (kbase - E_);
        plo = actH_lo + m * hstride + (kbase - E_);
      }
      a_hi[mt] = *reinterpret_cast<const bf16x8*>(phi + ko);
      a_lo[mt] = *reinterpret_cast<const bf16x8*>(plo + ko);
    }
#pragma unroll
    for (int nt = 0; nt < 4; ++nt) {
      int n = r0 + nt * 16 + l16;  // gate row
      b_hi[nt] = *reinterpret_cast<const bf16x8*>(W_hi + (size_t)n * wstride + kbase + ko);
      b_lo[nt] = *reinterpret_cast<const bf16x8*>(W_lo + (size_t)n * wstride + kbase + ko);
    }
#pragma unroll
    for (int mt = 0; mt < 4; ++mt)
#pragma unroll
      for (int nt = 0; nt < 4; ++nt) {
        acc[mt][nt] = __builtin_amdgcn_mfma_f32_16x16x32_bf16(a_hi[mt], b_hi[nt], acc[mt][nt], 0, 0, 0);
        acc[mt][nt] = __builtin_amdgcn_mfma_f32_16x16x32_bf16(a_lo[mt], b_hi[nt], acc[mt][nt], 0, 0, 0);
        acc[mt][nt] = __builtin_amdgcn_mfma_f32_16x16x32_bf16(a_hi[mt], b_lo[nt], acc[mt][nt], 0, 0, 0);
      }
  }

  // D layout: m(batch) = quad*4+reg, n(gate row) = l16
#pragma unroll
  for (int mt = 0; mt < 4; ++mt)
#pragma unroll
    for (int nt = 0; nt < 4; ++nt)
#pragma unroll
      for (int r = 0; r < 4; ++r) {
        int b = mt * 16 + quad * 4 + r;
        int row = rbase + r0 + nt * 16 + l16;
        partial[((size_t)s * B_ + b) * ROWS_TOT_ + row] = acc[mt][nt][r];
      }
}

// ---------------- per-step kernel B: vectorized reduce + pointwise ----------------
// 64 blocks (one per batch b) x 256 threads; thread owns 4 consecutive d.
// All partial/bias reads are f32x4; state in [b][d] layout -> fully coalesced
// vector reads/writes; p reduced per-block in LDS -> single store (no atomics).
// Gate-sum order identical to the proven kernel: bias first, slices ascending.
__global__ __launch_bounds__(256) void k_point2(
    const float* __restrict__ partial, float* __restrict__ c_l,
    float* __restrict__ h_f, uint16_t* __restrict__ h_hi, uint16_t* __restrict__ h_lo,
    float* __restrict__ c_s, uint16_t* __restrict__ hs_hi, uint16_t* __restrict__ hs_lo,
    float* __restrict__ p_acc, const float* __restrict__ rseq,
    const float* __restrict__ bihl, const float* __restrict__ bhhl,
    const float* __restrict__ bihs, const float* __restrict__ bhhs,
    const float* __restrict__ Wp, float* __restrict__ out_h, int t) {
  const int b = blockIdx.x;
  const int tid = threadIdx.x;
  const int d0 = tid * 4;

  // ---- large-cell gate sums (i,f,g,o), vectorized over 4 d's ----
  f32x4 g4[4];
#pragma unroll
  for (int g = 0; g < 4; ++g) {
    const int row = g * HL_ + d0;
    f32x4 v = *(const f32x4*)(bihl + row) + *(const f32x4*)(bhhl + row);
#pragma unroll
    for (int s = 0; s < SL_; ++s)
      v += *(const f32x4*)(partial + ((size_t)s * B_ + b) * ROWS_TOT_ + row);
    g4[g] = v;
  }

  const f32x4 cprev = *(const f32x4*)(c_l + b * HL_ + d0);
  const f32x4 hprev = *(const f32x4*)(h_f + b * HL_ + d0);   // prev large h (tail blend)

  // ---- small cell (threads with d0 < 256 only; wave-uniform branch) ----
  f32x4 hs_new = {0.f, 0.f, 0.f, 0.f}, cs_new = {0.f, 0.f, 0.f, 0.f};
  const bool hasS = (d0 < HS_);
  if (hasS) {
    f32x4 gs[4];
#pragma unroll
    for (int g = 0; g < 4; ++g) {
      const int row = ROWS_L_ + g * HS_ + d0;
      f32x4 v = *(const f32x4*)(bihs + g * HS_ + d0) + *(const f32x4*)(bhhs + g * HS_ + d0);
#pragma unroll
      for (int s = 0; s < SS_; ++s)
        v += *(const f32x4*)(partial + ((size_t)s * B_ + b) * ROWS_TOT_ + row);
      gs[g] = v;
    }
    const f32x4 csp = *(const f32x4*)(c_s + b * HS_ + d0);
    s16x4 shi, slo;
#pragma unroll
    for (int e = 0; e < 4; ++e) {
      float cs = sigm(gs[1][e]) * csp[e] + sigm(gs[0][e]) * tanhf(gs[2][e]);
      float hs = sigm(gs[3][e]) * tanhf(cs);
      cs_new[e] = cs; hs_new[e] = hs;
      uint16_t hi = f2bf(hs);
      shi[e] = (short)hi;
      slo[e] = (short)f2bf(hs - bf2f(hi));
    }
    *(f32x4*)(c_s + b * HS_ + d0) = cs_new;
    *(s16x4*)(hs_hi + b * HS_ + d0) = shi;
    *(s16x4*)(hs_lo + b * HS_ + d0) = slo;
  }

  // ---- pointwise + blend ----
  const float r0v = rseq[(t * B_ + b) * 2 + 0];
  const float r1v = rseq[(t * B_ + b) * 2 + 1];
  f32x4 cnv, hnv, cnext, hnext;
  float p0 = 0.f, p1 = 0.f;
  s16x4 hhi, hlo;
#pragma unroll
  for (int e = 0; e < 4; ++e) {
    const int d = d0 + e;
    float cn = sigm(g4[1][e]) * cprev[e] + sigm(g4[0][e]) * tanhf(g4[2][e]);
    float hn = sigm(g4[3][e]) * tanhf(cn);
    float hb = hasS ? hs_new[e] : hprev[e];
    float cb = hasS ? cs_new[e] : cn;
    float hx = r0v * hn + r1v * hb;
    float cx = r0v * cn + r1v * cb;
    cnv[e] = cn; hnv[e] = hn; cnext[e] = cx; hnext[e] = hx;
    uint16_t hi = f2bf(hx);
    hhi[e] = (short)hi;
    hlo[e] = (short)f2bf(hx - bf2f(hi));
    p0 += hn * Wp[E_ + d] + cn * Wp[E_ + HL_ + d];
    p1 += hn * Wp[(E_ + 2 * HL_) + E_ + d] + cn * Wp[(E_ + 2 * HL_) + E_ + HL_ + d];
  }
  *(f32x4*)(c_l + b * HL_ + d0) = cnext;
  *(f32x4*)(h_f + b * HL_ + d0) = hnext;
  *(s16x4*)(h_hi + b * HL_ + d0) = hhi;
  *(s16x4*)(h_lo + b * HL_ + d0) = hlo;
  *(f32x4*)(out_h + ((size_t)b * L_ + t) * HL_ + d0) = hnext;   // h_stack[b][t][d]

  // ---- block-level p reduction (one store, no atomics) ----
  __shared__ float s0[256], s1[256];
  s0[tid] = p0; s1[tid] = p1;
  __syncthreads();
  for (int off = 128; off > 0; off >>= 1) {
    if (tid < off) { s0[tid] += s0[tid + off]; s1[tid] += s1[tid + off]; }
    __syncthreads();
  }
  if (tid == 0) {
    p_acc[(t * B_ + b) * 2 + 0] = s0[0];
    p_acc[(t * B_ + b) * 2 + 1] = s1[0];
  }
}

// ---------------- final kernels ----------------

__global__ __launch_bounds__(256) void k_cls1(
    const float* __restrict__ h_f, const float* __restrict__ Wc1,
    const float* __restrict__ bc1, float* __restrict__ z1) {
  int idx = blockIdx.x * 256 + threadIdx.x;  // < 64*512
  int b = idx >> 9, j = idx & 511;
  float s = bc1[j];
  const float* hr = h_f + (size_t)b * HL_;   // h_f is [b][d]
  const float* wr = Wc1 + (size_t)j * HL_;
  for (int d = 0; d < HL_; ++d) s += fmaxf(hr[d], 0.f) * wr[d];
  z1[idx] = fmaxf(s, 0.f);
}

__global__ __launch_bounds__(64) void k_cls2(
    const float* __restrict__ z1, const float* __restrict__ Wc2,
    const float* __restrict__ bc2, float* __restrict__ out) {
  int b = blockIdx.x;
  int tid = threadIdx.x;
  __shared__ float sv[NC_];
  if (tid < NC_) {
    float s = bc2[tid];
    const float* zr = z1 + b * 512;
    const float* wr = Wc2 + tid * 512;
    for (int k = 0; k < 512; ++k) s += zr[k] * wr[k];
    sv[tid] = s;
  }
  __syncthreads();
  if (tid == 0) {
    float m = sv[0];
    for (int j = 1; j < NC_; ++j) m = fmaxf(m, sv[j]);
    float e[NC_], sum = 0.f;
    for (int j = 0; j < NC_; ++j) { e[j] = expf(sv[j] - m); sum += e[j]; }
    float inv = 1.0f / sum;
    for (int j = 0; j < NC_; ++j) out[b * NC_ + j] = e[j] * inv;
  }
}

__global__ __launch_bounds__(256) void k_pfinal(
    const float* __restrict__ p_acc, const float* __restrict__ Pe,
    const float* __restrict__ bp, float* __restrict__ out_p) {
  int idx = blockIdx.x * 256 + threadIdx.x;  // b*512+t
  int b = idx >> 9, t = idx & 511;
  int i2 = (t * B_ + b) * 2;
  float v0 = p_acc[i2 + 0] + Pe[i2 + 0] + bp[0];
  float v1 = p_acc[i2 + 1] + Pe[i2 + 1] + bp[1];
  float m = fmaxf(v0, v1);
  float e0 = expf(v0 - m), e1 = expf(v1 - m);
  float inv = 1.0f / (e0 + e1);
  out_p[(size_t)idx * 2 + 0] = e0 * inv;
  out_p[(size_t)idx * 2 + 1] = e1 * inv;
}

// ---------------- host ----------------
extern "C" void kernel_launch(void* const* d_in, const int* in_sizes, int n_in,
                              void* d_out, int out_size, void* d_ws, size_t ws_size,
                              hipStream_t stream) {
  const int*   x    = (const int*)d_in[0];
  const float* gum  = (const float*)d_in[1];
  const float* emb  = (const float*)d_in[2];
  const float* Wihl = (const float*)d_in[3];
  const float* Whhl = (const float*)d_in[4];
  const float* bihl = (const float*)d_in[5];
  const float* bhhl = (const float*)d_in[6];
  const float* Wihs = (const float*)d_in[7];
  const float* Whhs = (const float*)d_in[8];
  const float* bihs = (const float*)d_in[9];
  const float* bhhs = (const float*)d_in[10];
  const float* Wp   = (const float*)d_in[11];
  const float* bp   = (const float*)d_in[12];
  const float* Wc1  = (const float*)d_in[13];
  const float* bc1  = (const float*)d_in[14];
  const float* Wc2  = (const float*)d_in[15];
  const float* bc2  = (const float*)d_in[16];
  float* out = (float*)d_out;

  char* ws = (char*)d_ws;
  // workspace layout (bytes) — ~108 MB total (identical to the 10.68 ms version)
  uint16_t* Ahi   = (uint16_t*)(ws + 0);           //  33,554,432  [L][B][E]
  uint16_t* Alo   = (uint16_t*)(ws + 33554432);    //  33,554,432
  uint16_t* Wl_hi = (uint16_t*)(ws + 67108864);    //  12,582,912  [4096][1536]
  uint16_t* Wl_lo = (uint16_t*)(ws + 79691776);    //  12,582,912
  uint16_t* Ws_hi = (uint16_t*)(ws + 92274688);    //   1,572,864  [1024][768]
  uint16_t* Ws_lo = (uint16_t*)(ws + 93847552);    //   1,572,864
  float*    part  = (float*)   (ws + 95420416);    //  10,485,760  [8][64][5120]
  // state block (zeroed): 105,906,176 ..
  float*    c_l   = (float*)   (ws + 105906176);   //     262,144  [b][d]
  float*    h_f   = (float*)   (ws + 106168320);   //     262,144  [b][d]
  float*    c_s   = (float*)   (ws + 106430464);   //      65,536  [b][d]
  float*    p_acc = (float*)   (ws + 106496000);   //     262,144  [t][b][2]
  uint16_t* h_hi  = (uint16_t*)(ws + 106758144);   //     131,072  [b][d]
  uint16_t* h_lo  = (uint16_t*)(ws + 106889216);   //     131,072
  uint16_t* hs_hi = (uint16_t*)(ws + 107020288);   //      32,768
  uint16_t* hs_lo = (uint16_t*)(ws + 107053056);   //      32,768
  float*    Pe    = (float*)   (ws + 107085824);   //     262,144  [t][b][2]
  float*    rseq  = (float*)   (ws + 107347968);   //     262,144  [t][b][2]
  float*    z1    = (float*)   (ws + 107610112);   //     131,072  [64][512]

  float* out_logits = out;                          // 320
  float* out_h      = out + 320;                    // [B][L][HL]
  float* out_p      = out + 320 + (size_t)B_ * L_ * HL_;  // [B][L][2]

  // ---- setup ----
  {
    int n = ROWS_L_ * KL_ + ROWS_S_ * KS_;  // 7,077,888
    k_convw<<<(n + 255) / 256, 256, 0, stream>>>(Wihl, Whhl, Wihs, Whhs,
                                                 Wl_hi, Wl_lo, Ws_hi, Ws_lo);
  }
  k_embed<<<(L_ * B_ * E_) / 256, 256, 0, stream>>>(x, emb, Ahi, Alo);
  {
    int nwords = (107085824 - 105906176) / 4;  // state block words
    k_zero<<<(nwords + 255) / 256, 256, 0, stream>>>((uint32_t*)(ws + 105906176), nwords);
  }
  k_rseq<<<(L_ * B_) / 256, 256, 0, stream>>>(gum, rseq);
  k_pe<<<(L_ * B_) / 256, 256, 0, stream>>>(x, emb, Wp, Pe);

  // ---- sequential scan: 2 kernels per step (kernel boundary = grid sync) ----
  for (int t = 0; t < L_; ++t) {
    k_step_gemm<<<576, 64, 0, stream>>>(Ahi, Alo, h_hi, h_lo, hs_hi, hs_lo,
                                        Wl_hi, Wl_lo, Ws_hi, Ws_lo, part, t);
    k_point2<<<B_, 256, 0, stream>>>(part, c_l, h_f, h_hi, h_lo, c_s, hs_hi, hs_lo,
                                     p_acc, rseq, bihl, bhhl, bihs, bhhs,
                                     Wp, out_h, t);
  }

  // ---- epilogue ----
  k_cls1<<<(B_ * 512) / 256, 256, 0, stream>>>(h_f, Wc1, bc1, z1);
  k_cls2<<<B_, 64, 0, stream>>>(z1, Wc2, bc2, out_logits);
  k_pfinal<<<(B_ * L_) / 256, 256, 0, stream>>>(p_acc, Pe, bp, out_p);
}

// Round 4
// 11006.896 us; speedup vs baseline: 11.1414x; 1.1018x over previous
//
#include <hip/hip_runtime.h>
#include <stdint.h>
#include <stddef.h>

// ---------------- problem constants ----------------
#define B_   64
#define L_   512
#define E_   512
#define HL_  1024
#define HS_  256
#define NC_  5
#define KL_  (E_ + HL_)   // 1536  concat K for large cell
#define KS_  (E_ + HS_)   // 768   concat K for small cell
#define ROWS_L_ 4096      // 4*HL
#define ROWS_S_ 1024      // 4*HS
#define ROWS_TOT_ 5120
#define SL_  8            // K-slices large (192 each = 6 ksteps of 32)
#define SS_  4            // K-slices small (192 each)

typedef __attribute__((ext_vector_type(8))) short bf16x8;   // 8 bf16 in 4 VGPRs
typedef __attribute__((ext_vector_type(4))) float f32x4;

__device__ __forceinline__ uint16_t f2bf(float f) {
  union { float f; uint32_t u; } v; v.f = f;
  uint32_t r = v.u + 0x7FFFu + ((v.u >> 16) & 1u);
  return (uint16_t)(r >> 16);
}
__device__ __forceinline__ float bf2f(uint16_t h) {
  union { uint32_t u; float f; } v; v.u = ((uint32_t)h) << 16; return v.f;
}
__device__ __forceinline__ float sigm(float x) { return 1.0f / (1.0f + expf(-x)); }

// ---------------- setup kernels ----------------

// Build bf16 hi/lo concatenated weights: Wl[4096][1536] = [W_ih_l | W_hh_l],
// Ws[1024][768] = [W_ih_s | W_hh_s].  lo = round(v - hi) captures next 8 bits.
__global__ __launch_bounds__(256) void k_convw(
    const float* __restrict__ Wihl, const float* __restrict__ Whhl,
    const float* __restrict__ Wihs, const float* __restrict__ Whhs,
    uint16_t* __restrict__ Wl_hi, uint16_t* __restrict__ Wl_lo,
    uint16_t* __restrict__ Ws_hi, uint16_t* __restrict__ Ws_lo) {
  const int N1 = ROWS_L_ * KL_;          // 6291456
  const int N2 = ROWS_S_ * KS_;          // 786432
  int idx = blockIdx.x * 256 + threadIdx.x;
  if (idx < N1) {
    int row = idx / KL_, k = idx - row * KL_;
    float v = (k < E_) ? Wihl[row * E_ + k] : Whhl[row * HL_ + (k - E_)];
    uint16_t hi = f2bf(v);
    Wl_hi[idx] = hi;
    Wl_lo[idx] = f2bf(v - bf2f(hi));
  } else if (idx < N1 + N2) {
    int j = idx - N1;
    int row = j / KS_, k = j - row * KS_;
    float v = (k < E_) ? Wihs[row * E_ + k] : Whhs[row * HS_ + (k - E_)];
    uint16_t hi = f2bf(v);
    Ws_hi[j] = hi;
    Ws_lo[j] = f2bf(v - bf2f(hi));
  }
}

// Gather embedding rows into bf16 hi/lo: A[t][b][k]
__global__ __launch_bounds__(256) void k_embed(
    const int* __restrict__ x, const float* __restrict__ emb,
    uint16_t* __restrict__ Ahi, uint16_t* __restrict__ Alo) {
  int idx = blockIdx.x * 256 + threadIdx.x;       // < L*B*E = 16.7M
  int t = idx >> 15;                               // /(B*E)
  int rem = idx & 32767;
  int b = rem >> 9;                                // /E
  int k = rem & 511;
  int tok = x[b * L_ + t];
  float v = emb[(size_t)tok * E_ + k];
  uint16_t hi = f2bf(v);
  Ahi[idx] = hi;
  Alo[idx] = f2bf(v - bf2f(hi));
}

// Zero the state block — ws is poisoned 0xAA.
__global__ __launch_bounds__(256) void k_zero(uint32_t* __restrict__ p, int nwords) {
  int idx = blockIdx.x * 256 + threadIdx.x;
  if (idx < nwords) p[idx] = 0u;
}

// r_seq[t][b][2] = softmax(-log(-log(u)))   (tau = 1; p_t faithfully unused)
__global__ __launch_bounds__(256) void k_rseq(
    const float* __restrict__ gum, float* __restrict__ rseq) {
  int idx = blockIdx.x * 256 + threadIdx.x;       // t*64+b
  int t = idx >> 6, b = idx & 63;
  float u0 = gum[(b * L_ + t) * 2 + 0];
  float u1 = gum[(b * L_ + t) * 2 + 1];
  float g0 = -logf(-logf(u0));
  float g1 = -logf(-logf(u1));
  float m = fmaxf(g0, g1);
  float e0 = expf(g0 - m), e1 = expf(g1 - m);
  float inv = 1.0f / (e0 + e1);
  rseq[idx * 2 + 0] = e0 * inv;
  rseq[idx * 2 + 1] = e1 * inv;
}

// Pe[t][b][j] = e_t[b] . W_p[j][0:512]  computed from fp32 emb (exact)
__global__ __launch_bounds__(256) void k_pe(
    const int* __restrict__ x, const float* __restrict__ emb,
    const float* __restrict__ Wp, float* __restrict__ Pe) {
  int idx = blockIdx.x * 256 + threadIdx.x;       // t*64+b
  int t = idx >> 6, b = idx & 63;
  int tok = x[b * L_ + t];
  const float* row = emb + (size_t)tok * E_;
  float a0 = 0.f, a1 = 0.f;
  for (int k = 0; k < E_; ++k) {
    float e = row[k];
    a0 += e * Wp[k];
    a1 += e * Wp[(E_ + 2 * HL_) + k];
  }
  Pe[idx * 2 + 0] = a0;
  Pe[idx * 2 + 1] = a1;
}

// ---------------- per-step kernel A: K-sliced 3-term split-bf16 MFMA GEMM ----
// acc += Ahi.Whi + Alo.Whi + Ahi.Wlo   (fp32-accurate to ~2^-16 rel)
// 32-row tiles for occupancy: 1152 single-wave blocks (~1.1 waves/SIMD vs 0.56
// at 64-row tiles) — every SIMD occupied, L3 load latency 2x better hidden.
// blocks 0..1023   : large cell, rowtile rt=bid>>3 (32 rows), slice s=bid&7
// blocks 1024..1151: small cell, rowtile rt=(bid-1024)>>2 (32 rows), s=&3
// Numerics bit-identical to the 64-row version (same per-row slice sums).
__global__ __launch_bounds__(64) void k_step_gemm(
    const uint16_t* __restrict__ Ahi, const uint16_t* __restrict__ Alo,
    const uint16_t* __restrict__ h_hi, const uint16_t* __restrict__ h_lo,
    const uint16_t* __restrict__ hs_hi, const uint16_t* __restrict__ hs_lo,
    const uint16_t* __restrict__ Wl_hi, const uint16_t* __restrict__ Wl_lo,
    const uint16_t* __restrict__ Ws_hi, const uint16_t* __restrict__ Ws_lo,
    float* __restrict__ partial, int t) {
  int bid = blockIdx.x;
  int lane = threadIdx.x;
  int quad = lane >> 4, l16 = lane & 15;
  const uint16_t* actE_hi = Ahi + (size_t)t * (B_ * E_);
  const uint16_t* actE_lo = Alo + (size_t)t * (B_ * E_);
  const uint16_t *actH_hi, *actH_lo, *W_hi, *W_lo;
  int r0, s, wstride, hstride, rbase;
  if (bid < 1024) {
    int rt = bid >> 3; s = bid & 7;
    r0 = rt * 32; W_hi = Wl_hi; W_lo = Wl_lo; wstride = KL_;
    actH_hi = h_hi; actH_lo = h_lo; hstride = HL_; rbase = 0;
  } else {
    int b2 = bid - 1024;
    int rt = b2 >> 2; s = b2 & 3;
    r0 = rt * 32; W_hi = Ws_hi; W_lo = Ws_lo; wstride = KS_;
    actH_hi = hs_hi; actH_lo = hs_lo; hstride = HS_; rbase = ROWS_L_;
  }
  int k0 = s * 192;

  f32x4 acc[4][2];
#pragma unroll
  for (int mt = 0; mt < 4; ++mt)
#pragma unroll
    for (int nt = 0; nt < 2; ++nt) {
      acc[mt][nt][0] = 0.f; acc[mt][nt][1] = 0.f;
      acc[mt][nt][2] = 0.f; acc[mt][nt][3] = 0.f;
    }

  int ko = quad * 8;
#pragma unroll
  for (int kk = 0; kk < 6; ++kk) {
    int kbase = k0 + kk * 32;
    bf16x8 a_hi[4], a_lo[4], b_hi[2], b_lo[2];
#pragma unroll
    for (int mt = 0; mt < 4; ++mt) {
      int m = mt * 16 + l16;  // batch
      const uint16_t* phi;
      const uint16_t* plo;
      if (kbase < E_) {
        phi = actE_hi + m * E_ + kbase;
        plo = actE_lo + m * E_ + kbase;
      } else {
        phi = actH_hi + m * hstride + (kbase - E_);
        plo = actH_lo + m * hstride + (kbase - E_);
      }
      a_hi[mt] = *reinterpret_cast<const bf16x8*>(phi + ko);
      a_lo[mt] = *reinterpret_cast<const bf16x8*>(plo + ko);
    }
#pragma unroll
    for (int nt = 0; nt < 2; ++nt) {
      int n = r0 + nt * 16 + l16;  // gate row
      b_hi[nt] = *reinterpret_cast<const bf16x8*>(W_hi + (size_t)n * wstride + kbase + ko);
      b_lo[nt] = *reinterpret_cast<const bf16x8*>(W_lo + (size_t)n * wstride + kbase + ko);
    }
#pragma unroll
    for (int mt = 0; mt < 4; ++mt)
#pragma unroll
      for (int nt = 0; nt < 2; ++nt) {
        acc[mt][nt] = __builtin_amdgcn_mfma_f32_16x16x32_bf16(a_hi[mt], b_hi[nt], acc[mt][nt], 0, 0, 0);
        acc[mt][nt] = __builtin_amdgcn_mfma_f32_16x16x32_bf16(a_lo[mt], b_hi[nt], acc[mt][nt], 0, 0, 0);
        acc[mt][nt] = __builtin_amdgcn_mfma_f32_16x16x32_bf16(a_hi[mt], b_lo[nt], acc[mt][nt], 0, 0, 0);
      }
  }

  // D layout: m(batch) = quad*4+reg, n(gate row) = l16
#pragma unroll
  for (int mt = 0; mt < 4; ++mt)
#pragma unroll
    for (int nt = 0; nt < 2; ++nt)
#pragma unroll
      for (int r = 0; r < 4; ++r) {
        int b = mt * 16 + quad * 4 + r;
        int row = rbase + r0 + nt * 16 + l16;
        partial[((size_t)s * B_ + b) * ROWS_TOT_ + row] = acc[mt][nt][r];
      }
}

// ---------------- per-step kernel B: reduce + pointwise + blend + p ----------------
// (verbatim from the proven 10.68 ms version: 256 blocks x 256 threads)
__global__ __launch_bounds__(256) void k_step_point(
    const float* __restrict__ partial, float* __restrict__ c_l,
    float* __restrict__ h_f, uint16_t* __restrict__ h_hi, uint16_t* __restrict__ h_lo,
    float* __restrict__ c_s, uint16_t* __restrict__ hs_hi, uint16_t* __restrict__ hs_lo,
    float* __restrict__ p_acc, const float* __restrict__ rseq,
    const float* __restrict__ bihl, const float* __restrict__ bhhl,
    const float* __restrict__ bihs, const float* __restrict__ bhhs,
    const float* __restrict__ Wp, float* __restrict__ out_h, int t) {
  int bb = blockIdx.x >> 2, cc = blockIdx.x & 3;
  int tid = threadIdx.x;
  int d = cc * 256 + tid;

  // large cell gates (i,f,g,o)
  float g4[4];
#pragma unroll
  for (int g = 0; g < 4; ++g) {
    int row = g * HL_ + d;
    float v = bihl[row] + bhhl[row];
#pragma unroll
    for (int s = 0; s < SL_; ++s)
      v += partial[((size_t)s * B_ + bb) * ROWS_TOT_ + row];
    g4[g] = v;
  }
  float cprev = c_l[bb * HL_ + d];
  float cn = sigm(g4[1]) * cprev + sigm(g4[0]) * tanhf(g4[2]);
  float hn = sigm(g4[3]) * tanhf(cn);

  // small cell (only d<256 chunk)
  float hs_new = 0.f, cs_new = 0.f;
  if (cc == 0) {
    float gs[4];
#pragma unroll
    for (int g = 0; g < 4; ++g) {
      int row = ROWS_L_ + g * HS_ + d;
      float v = bihs[g * HS_ + d] + bhhs[g * HS_ + d];
#pragma unroll
      for (int s = 0; s < SS_; ++s)
        v += partial[((size_t)s * B_ + bb) * ROWS_TOT_ + row];
      gs[g] = v;
    }
    float csp = c_s[bb * HS_ + d];
    cs_new = sigm(gs[1]) * csp + sigm(gs[0]) * tanhf(gs[2]);
    hs_new = sigm(gs[3]) * tanhf(cs_new);
    c_s[bb * HS_ + d] = cs_new;
    uint16_t hi = f2bf(hs_new);
    hs_hi[bb * HS_ + d] = hi;
    hs_lo[bb * HS_ + d] = f2bf(hs_new - bf2f(hi));
  }

  // blend (r depends only on u — precomputed)
  float r0v = rseq[(t * B_ + bb) * 2 + 0];
  float r1v = rseq[(t * B_ + bb) * 2 + 1];
  float hb = (cc == 0) ? hs_new : h_f[bb * HL_ + d];   // tail = prev carry h
  float cb = (cc == 0) ? cs_new : cn;                  // tail = c_l_new
  float hnext = r0v * hn + r1v * hb;
  float cnext = r0v * cn + r1v * cb;

  c_l[bb * HL_ + d] = cnext;
  h_f[bb * HL_ + d] = hnext;
  uint16_t hhi = f2bf(hnext);
  h_hi[bb * HL_ + d] = hhi;
  h_lo[bb * HL_ + d] = f2bf(hnext - bf2f(hhi));
  out_h[((size_t)bb * L_ + t) * HL_ + d] = hnext;      // h_stack[b][t][d]

  // p_t partials over the h/c part: p[j] += hn*Wp[j][512+d] + cn*Wp[j][1536+d]
  float p0 = hn * Wp[E_ + d] + cn * Wp[E_ + HL_ + d];
  float p1 = hn * Wp[(E_ + 2 * HL_) + E_ + d] + cn * Wp[(E_ + 2 * HL_) + E_ + HL_ + d];
  __shared__ float s0[256], s1[256];
  s0[tid] = p0; s1[tid] = p1;
  __syncthreads();
  for (int off = 128; off > 0; off >>= 1) {
    if (tid < off) { s0[tid] += s0[tid + off]; s1[tid] += s1[tid + off]; }
    __syncthreads();
  }
  if (tid == 0) {
    atomicAdd(&p_acc[(t * B_ + bb) * 2 + 0], s0[0]);
    atomicAdd(&p_acc[(t * B_ + bb) * 2 + 1], s1[0]);
  }
}

// ---------------- final kernels ----------------

__global__ __launch_bounds__(256) void k_cls1(
    const float* __restrict__ h_f, const float* __restrict__ Wc1,
    const float* __restrict__ bc1, float* __restrict__ z1) {
  int idx = blockIdx.x * 256 + threadIdx.x;  // < 64*512
  int b = idx >> 9, j = idx & 511;
  float s = bc1[j];
  const float* hr = h_f + b * HL_;
  const float* wr = Wc1 + (size_t)j * HL_;
  for (int d = 0; d < HL_; ++d) s += fmaxf(hr[d], 0.f) * wr[d];
  z1[idx] = fmaxf(s, 0.f);
}

__global__ __launch_bounds__(64) void k_cls2(
    const float* __restrict__ z1, const float* __restrict__ Wc2,
    const float* __restrict__ bc2, float* __restrict__ out) {
  int b = blockIdx.x;
  int tid = threadIdx.x;
  __shared__ float sv[NC_];
  if (tid < NC_) {
    float s = bc2[tid];
    const float* zr = z1 + b * 512;
    const float* wr = Wc2 + tid * 512;
    for (int k = 0; k < 512; ++k) s += zr[k] * wr[k];
    sv[tid] = s;
  }
  __syncthreads();
  if (tid == 0) {
    float m = sv[0];
    for (int j = 1; j < NC_; ++j) m = fmaxf(m, sv[j]);
    float e[NC_], sum = 0.f;
    for (int j = 0; j < NC_; ++j) { e[j] = expf(sv[j] - m); sum += e[j]; }
    float inv = 1.0f / sum;
    for (int j = 0; j < NC_; ++j) out[b * NC_ + j] = e[j] * inv;
  }
}

__global__ __launch_bounds__(256) void k_pfinal(
    const float* __restrict__ p_acc, const float* __restrict__ Pe,
    const float* __restrict__ bp, float* __restrict__ out_p) {
  int idx = blockIdx.x * 256 + threadIdx.x;  // b*512+t
  int b = idx >> 9, t = idx & 511;
  int i2 = (t * B_ + b) * 2;
  float v0 = p_acc[i2 + 0] + Pe[i2 + 0] + bp[0];
  float v1 = p_acc[i2 + 1] + Pe[i2 + 1] + bp[1];
  float m = fmaxf(v0, v1);
  float e0 = expf(v0 - m), e1 = expf(v1 - m);
  float inv = 1.0f / (e0 + e1);
  out_p[(size_t)idx * 2 + 0] = e0 * inv;
  out_p[(size_t)idx * 2 + 1] = e1 * inv;
}

// ---------------- host ----------------
extern "C" void kernel_launch(void* const* d_in, const int* in_sizes, int n_in,
                              void* d_out, int out_size, void* d_ws, size_t ws_size,
                              hipStream_t stream) {
  const int*   x    = (const int*)d_in[0];
  const float* gum  = (const float*)d_in[1];
  const float* emb  = (const float*)d_in[2];
  const float* Wihl = (const float*)d_in[3];
  const float* Whhl = (const float*)d_in[4];
  const float* bihl = (const float*)d_in[5];
  const float* bhhl = (const float*)d_in[6];
  const float* Wihs = (const float*)d_in[7];
  const float* Whhs = (const float*)d_in[8];
  const float* bihs = (const float*)d_in[9];
  const float* bhhs = (const float*)d_in[10];
  const float* Wp   = (const float*)d_in[11];
  const float* bp   = (const float*)d_in[12];
  const float* Wc1  = (const float*)d_in[13];
  const float* bc1  = (const float*)d_in[14];
  const float* Wc2  = (const float*)d_in[15];
  const float* bc2  = (const float*)d_in[16];
  float* out = (float*)d_out;

  char* ws = (char*)d_ws;
  // workspace layout (bytes) — ~108 MB total (identical to the 10.68 ms version)
  uint16_t* Ahi   = (uint16_t*)(ws + 0);           //  33,554,432  [L][B][E]
  uint16_t* Alo   = (uint16_t*)(ws + 33554432);    //  33,554,432
  uint16_t* Wl_hi = (uint16_t*)(ws + 67108864);    //  12,582,912  [4096][1536]
  uint16_t* Wl_lo = (uint16_t*)(ws + 79691776);    //  12,582,912
  uint16_t* Ws_hi = (uint16_t*)(ws + 92274688);    //   1,572,864  [1024][768]
  uint16_t* Ws_lo = (uint16_t*)(ws + 93847552);    //   1,572,864
  float*    part  = (float*)   (ws + 95420416);    //  10,485,760  [8][64][5120]
  // state block (zeroed): 105,906,176 ..
  float*    c_l   = (float*)   (ws + 105906176);   //     262,144
  float*    h_f   = (float*)   (ws + 106168320);   //     262,144
  float*    c_s   = (float*)   (ws + 106430464);   //      65,536
  float*    p_acc = (float*)   (ws + 106496000);   //     262,144  [L][B][2]
  uint16_t* h_hi  = (uint16_t*)(ws + 106758144);   //     131,072
  uint16_t* h_lo  = (uint16_t*)(ws + 106889216);   //     131,072
  uint16_t* hs_hi = (uint16_t*)(ws + 107020288);   //      32,768
  uint16_t* hs_lo = (uint16_t*)(ws + 107053056);   //      32,768
  float*    Pe    = (float*)   (ws + 107085824);   //     262,144  [L][B][2]
  float*    rseq  = (float*)   (ws + 107347968);   //     262,144  [L][B][2]
  float*    z1    = (float*)   (ws + 107610112);   //     131,072  [64][512]

  float* out_logits = out;                          // 320
  float* out_h      = out + 320;                    // [B][L][HL]
  float* out_p      = out + 320 + (size_t)B_ * L_ * HL_;  // [B][L][2]

  // ---- setup ----
  {
    int n = ROWS_L_ * KL_ + ROWS_S_ * KS_;  // 7,077,888
    k_convw<<<(n + 255) / 256, 256, 0, stream>>>(Wihl, Whhl, Wihs, Whhs,
                                                 Wl_hi, Wl_lo, Ws_hi, Ws_lo);
  }
  k_embed<<<(L_ * B_ * E_) / 256, 256, 0, stream>>>(x, emb, Ahi, Alo);
  {
    int nwords = (107085824 - 105906176) / 4;  // state block words
    k_zero<<<(nwords + 255) / 256, 256, 0, stream>>>((uint32_t*)(ws + 105906176), nwords);
  }
  k_rseq<<<(L_ * B_) / 256, 256, 0, stream>>>(gum, rseq);
  k_pe<<<(L_ * B_) / 256, 256, 0, stream>>>(x, emb, Wp, Pe);

  // ---- sequential scan: 2 kernels per step (kernel boundary = grid sync) ----
  for (int t = 0; t < L_; ++t) {
    k_step_gemm<<<1152, 64, 0, stream>>>(Ahi, Alo, h_hi, h_lo, hs_hi, hs_lo,
                                         Wl_hi, Wl_lo, Ws_hi, Ws_lo, part, t);
    k_step_point<<<256, 256, 0, stream>>>(part, c_l, h_f, h_hi, h_lo, c_s, hs_hi, hs_lo,
                                          p_acc, rseq, bihl, bhhl, bihs, bhhs,
                                          Wp, out_h, t);
  }

  // ---- epilogue ----
  k_cls1<<<(B_ * 512) / 256, 256, 0, stream>>>(h_f, Wc1, bc1, z1);
  k_cls2<<<B_, 64, 0, stream>>>(z1, Wc2, bc2, out_logits);
  k_pfinal<<<(B_ * L_) / 256, 256, 0, stream>>>(p_acc, Pe, bp, out_p);
}